// Round 6
// baseline (231.145 us; speedup 1.0000x reference)
//
#include <hip/hip_runtime.h>

// KDA delta-rule state update, B=H=32, K=V=256, fp32.
// out[k,v] = g[k]*S[k,v] + cb[k]*(val[v] - kt[v]),
//   w[k] = g[k]*key[k], cb[k] = beta*key[k], kt[v] = sum_k w[k]*S[k,v].
//
// Barrier-free main loop: kt reduction is fully in-wave.
// Lane = (r0 in [0,16)) x (c in [0,4)): each lane owns 16 rows x 1 f32x4
// column; local k-accumulate then 4-round shfl_xor butterfly over r0.
// 16 autonomous waves/CU interleave their load/compute/store phases, so
// the VMEM pipe never idles on a phase turn (copy-kernel-style TLP).

#define KD 256
#define VD 256
#define VD4 (VD / 4)   // 64 f32x4 per row

typedef float f32x4 __attribute__((ext_vector_type(4)));
typedef float f32x2 __attribute__((ext_vector_type(2)));

__global__ __launch_bounds__(256, 4)
void kda_update_kernel(const float* __restrict__ state,
                       const float* __restrict__ keys,
                       const float* __restrict__ values,
                       const float* __restrict__ gates,
                       const float* __restrict__ beta,
                       float* __restrict__ out)
{
    const int bh = blockIdx.x;                  // one block per (b,h) tile
    const size_t toff = (size_t)bh * (KD * VD);
    const f32x4* __restrict__ S4 = (const f32x4*)(state + toff);
    f32x4* __restrict__ O4 = (f32x4*)(out + toff);
    const f32x4* __restrict__ V4 = (const f32x4*)(values + (size_t)bh * VD);

    __shared__ float s_w[KD];    // g*key
    __shared__ f32x2 s_gc[KD];   // {g, beta*key}

    const int t    = threadIdx.x;
    const int wv   = t >> 6;     // wave 0..3
    const int lane = t & 63;
    const int c    = lane & 3;   // f32x4 col within wave's 4
    const int r0   = lane >> 2;  // row group 0..15

    // Stage per-row scalars once (before any tile traffic, so this barrier
    // drains nothing of consequence).
    {
        const float g = gates[bh * KD + t];
        const float k = keys[bh * KD + t];
        s_w[t] = g * k;
        f32x2 gc;
        gc.x = g;
        gc.y = beta[bh] * k;
        s_gc[t] = gc;
    }
    __syncthreads();   // the ONLY block-wide barrier

    // Each wave covers 4 f32x4 cols per iteration; 4 iterations sweep the
    // block's 64 f32x4 cols. No inter-wave coupling below this point.
    for (int it = 0; it < 4; ++it) {
        const int c4 = it * 16 + wv * 4 + c;   // this lane's f32x4 column

        const f32x4 vv = V4[c4];               // small, L1/L2-resident

        f32x4 s[16];
#pragma unroll
        for (int j = 0; j < 16; ++j)
            s[j] = __builtin_nontemporal_load(&S4[(size_t)(r0 + 16 * j) * VD4 + c4]);

        // local kt partial over this lane's 16 rows
        f32x4 p = (f32x4)(0.f);
#pragma unroll
        for (int j = 0; j < 16; ++j) {
            const float w = s_w[r0 + 16 * j];
            p.x = fmaf(w, s[j].x, p.x);
            p.y = fmaf(w, s[j].y, p.y);
            p.z = fmaf(w, s[j].z, p.z);
            p.w = fmaf(w, s[j].w, p.w);
        }

        // in-wave butterfly over the 16 r0-groups (lanes differ in bits 2..5)
#pragma unroll
        for (int m = 4; m <= 32; m <<= 1) {
            p.x += __shfl_xor(p.x, m, 64);
            p.y += __shfl_xor(p.y, m, 64);
            p.z += __shfl_xor(p.z, m, 64);
            p.w += __shfl_xor(p.w, m, 64);
        }

        f32x4 d;
        d.x = vv.x - p.x;
        d.y = vv.y - p.y;
        d.z = vv.z - p.z;
        d.w = vv.w - p.w;

#pragma unroll
        for (int j = 0; j < 16; ++j) {
            const int k = r0 + 16 * j;
            const f32x2 gc = s_gc[k];
            f32x4 o;
            o.x = fmaf(gc.x, s[j].x, gc.y * d.x);
            o.y = fmaf(gc.x, s[j].y, gc.y * d.y);
            o.z = fmaf(gc.x, s[j].z, gc.y * d.z);
            o.w = fmaf(gc.x, s[j].w, gc.y * d.w);
            __builtin_nontemporal_store(o, &O4[(size_t)k * VD4 + c4]);
        }
    }
}

extern "C" void kernel_launch(void* const* d_in, const int* in_sizes, int n_in,
                              void* d_out, int out_size, void* d_ws, size_t ws_size,
                              hipStream_t stream) {
    const float* state  = (const float*)d_in[0];
    const float* keys   = (const float*)d_in[1];
    const float* values = (const float*)d_in[2];
    const float* gates  = (const float*)d_in[3];
    const float* beta   = (const float*)d_in[4];
    float* out = (float*)d_out;

    dim3 grid(32 * 32);   // one block per (b,h) tile; 4 resident blocks/CU
    dim3 block(256);
    hipLaunchKernelGGL(kda_update_kernel, grid, block, 0, stream,
                       state, keys, values, gates, beta, out);
}

// Round 7
// 108.840 us; speedup vs baseline: 2.1237x; 2.1237x over previous
//
#include <hip/hip_runtime.h>

// KDA delta-rule state update, B=H=32, K=V=256, fp32.
// out[k,v] = g[k]*S[k,v] + beta*key[k]*(val[v] - kt[v]),
// kt[v] = sum_k g[k]*key[k]*S[k,v]   (column-independent in v).
//
// R7 = R5 structure exactly (two 32-float v-slices per 256-thread block,
// depth-2 software pipeline, lgkm-only barriers) with ONE change:
// non-temporal load/store flags REMOVED (plain global accesses) to A/B
// whether NT was capping effective HBM bandwidth at ~5.1 TB/s.

#define KD 256
#define VD 256
#define SW 8    // f32x4 columns per slice (32 floats)

typedef float f32x4 __attribute__((ext_vector_type(4)));

__device__ __forceinline__ f32x4 shfl_xor4(f32x4 v, int mask) {
    f32x4 r;
    r.x = __shfl_xor(v.x, mask, 64);
    r.y = __shfl_xor(v.y, mask, 64);
    r.z = __shfl_xor(v.z, mask, 64);
    r.w = __shfl_xor(v.w, mask, 64);
    return r;
}

// barrier that drains LDS ops only -- in-flight global loads/stores survive
__device__ __forceinline__ void lds_barrier() {
    asm volatile("s_waitcnt lgkmcnt(0)" ::: "memory");
    __builtin_amdgcn_s_barrier();
}

__global__ __launch_bounds__(256, 4)
void kda_update_kernel(const float* __restrict__ state,
                       const float* __restrict__ keys,
                       const float* __restrict__ values,
                       const float* __restrict__ gates,
                       const float* __restrict__ beta,
                       float* __restrict__ out)
{
    const int bid = blockIdx.x;
    const int bh  = bid >> 2;        // (b,h) tile
    const int sp  = bid & 3;         // slice pair -> slices 2sp, 2sp+1
    const size_t toff = (size_t)bh * (KD * VD);
    const f32x4* __restrict__ S4 = (const f32x4*)(state + toff);
    f32x4* __restrict__ O4 = (f32x4*)(out + toff);
    const f32x4* __restrict__ V4 = (const f32x4*)(values + (size_t)bh * VD);

    __shared__ float s_g[KD];          // alpha
    __shared__ float s_w[KD];          // alpha*key
    __shared__ float s_c[KD];          // beta*key
    __shared__ f32x4 s_redA[4][SW];    // cross-wave kt partials, slice A
    __shared__ f32x4 s_redB[4][SW];    // cross-wave kt partials, slice B

    const int t    = threadIdx.x;
    const int lane = t & 63;
    const int wv   = t >> 6;           // wave 0..3
    const int c    = t & (SW - 1);     // f32x4 col within slice
    const int r0   = t >> 3;           // rowgroup 0..31
    const int cA   = (2 * sp)     * SW + c;
    const int cB   = (2 * sp + 1) * SW + c;

    // ---- stage per-row scalars FIRST ----
    {
        const float g = gates[bh * KD + t];
        const float k = keys[bh * KD + t];
        s_g[t] = g;
        s_w[t] = g * k;
        s_c[t] = beta[bh] * k;
    }
    lds_barrier();

    // ---- issue values, then A, then B tile loads ----
    const f32x4 vA = V4[cA];
    const f32x4 vB = V4[cB];

    f32x4 sA[8], sB[8];
#pragma unroll
    for (int j = 0; j < 8; ++j)
        sA[j] = S4[(size_t)(r0 + 32 * j) * (VD / 4) + cA];
#pragma unroll
    for (int j = 0; j < 8; ++j)
        sB[j] = S4[(size_t)(r0 + 32 * j) * (VD / 4) + cB];

    // ---- slice A: partial kt (B's loads remain in flight) ----
    f32x4 p = (f32x4)(0.f);
#pragma unroll
    for (int j = 0; j < 8; ++j) {
        const float w = s_w[r0 + 32 * j];
        p.x = fmaf(w, sA[j].x, p.x);
        p.y = fmaf(w, sA[j].y, p.y);
        p.z = fmaf(w, sA[j].z, p.z);
        p.w = fmaf(w, sA[j].w, p.w);
    }
    p += shfl_xor4(p, 8);
    p += shfl_xor4(p, 16);
    p += shfl_xor4(p, 32);
    if (lane < SW) s_redA[wv][lane] = p;
    lds_barrier();

    f32x4 ktA = s_redA[0][c];
    {
        const f32x4 q1 = s_redA[1][c], q2 = s_redA[2][c], q3 = s_redA[3][c];
        ktA.x += q1.x + q2.x + q3.x;
        ktA.y += q1.y + q2.y + q3.y;
        ktA.z += q1.z + q2.z + q3.z;
        ktA.w += q1.w + q2.w + q3.w;
    }
    f32x4 dA;
    dA.x = vA.x - ktA.x; dA.y = vA.y - ktA.y; dA.z = vA.z - ktA.z; dA.w = vA.w - ktA.w;

    // ---- store A ----
#pragma unroll
    for (int j = 0; j < 8; ++j) {
        const int k = r0 + 32 * j;
        const float g  = s_g[k];
        const float cb = s_c[k];
        f32x4 o;
        o.x = fmaf(g, sA[j].x, cb * dA.x);
        o.y = fmaf(g, sA[j].y, cb * dA.y);
        o.z = fmaf(g, sA[j].z, cb * dA.z);
        o.w = fmaf(g, sA[j].w, cb * dA.w);
        O4[(size_t)k * (VD / 4) + cA] = o;
    }

    // ---- slice B ----
    f32x4 q = (f32x4)(0.f);
#pragma unroll
    for (int j = 0; j < 8; ++j) {
        const float w = s_w[r0 + 32 * j];
        q.x = fmaf(w, sB[j].x, q.x);
        q.y = fmaf(w, sB[j].y, q.y);
        q.z = fmaf(w, sB[j].z, q.z);
        q.w = fmaf(w, sB[j].w, q.w);
    }
    q += shfl_xor4(q, 8);
    q += shfl_xor4(q, 16);
    q += shfl_xor4(q, 32);
    if (lane < SW) s_redB[wv][lane] = q;
    lds_barrier();

    f32x4 ktB = s_redB[0][c];
    {
        const f32x4 q1 = s_redB[1][c], q2 = s_redB[2][c], q3 = s_redB[3][c];
        ktB.x += q1.x + q2.x + q3.x;
        ktB.y += q1.y + q2.y + q3.y;
        ktB.z += q1.z + q2.z + q3.z;
        ktB.w += q1.w + q2.w + q3.w;
    }
    f32x4 dB;
    dB.x = vB.x - ktB.x; dB.y = vB.y - ktB.y; dB.z = vB.z - ktB.z; dB.w = vB.w - ktB.w;

#pragma unroll
    for (int j = 0; j < 8; ++j) {
        const int k = r0 + 32 * j;
        const float g  = s_g[k];
        const float cb = s_c[k];
        f32x4 o;
        o.x = fmaf(g, sB[j].x, cb * dB.x);
        o.y = fmaf(g, sB[j].y, cb * dB.y);
        o.z = fmaf(g, sB[j].z, cb * dB.z);
        o.w = fmaf(g, sB[j].w, cb * dB.w);
        O4[(size_t)k * (VD / 4) + cB] = o;
    }
}

extern "C" void kernel_launch(void* const* d_in, const int* in_sizes, int n_in,
                              void* d_out, int out_size, void* d_ws, size_t ws_size,
                              hipStream_t stream) {
    const float* state  = (const float*)d_in[0];
    const float* keys   = (const float*)d_in[1];
    const float* values = (const float*)d_in[2];
    const float* gates  = (const float*)d_in[3];
    const float* beta   = (const float*)d_in[4];
    float* out = (float*)d_out;

    dim3 grid(32 * 32 * 4);  // (b,h) x 4 slice-pairs
    dim3 block(256);
    hipLaunchKernelGGL(kda_update_kernel, grid, block, 0, stream,
                       state, keys, values, gates, beta, out);
}